// Round 1
// 436.536 us; speedup vs baseline: 1.0190x; 1.0190x over previous
//
#include <hip/hip_runtime.h>
#include <hip/hip_bf16.h>

#define NN 50000
#define EE 400000
#define NB 196  // ceil(NN/256)

typedef __bf16 bf16_8 __attribute__((ext_vector_type(8)));
typedef float f32x4 __attribute__((ext_vector_type(4)));

// ---------------------------------------------------------------- prep (fused)
// [0,1563): f2b; [1563,1691): tr0; [1691,1947): tr1; 1947: ve0; 1948: ve1;
// [1949, 1949+1563): degree count (cnt zeroed by memset before launch)
__global__ __launch_bounds__(256) void prep_kernel(
    const float* __restrict__ features, __bf16* __restrict__ fbf,
    const float* __restrict__ W0, const float* __restrict__ Wres0, __bf16* __restrict__ Bt0,
    const float* __restrict__ W1, __bf16* __restrict__ Bt1,
    const float* __restrict__ We0, const float* __restrict__ ae0, float* __restrict__ Ve0,
    const float* __restrict__ We1, const float* __restrict__ ae1, float* __restrict__ Ve1,
    const int* __restrict__ dst, int* __restrict__ cnt) {
  int b = blockIdx.x;
  int t = threadIdx.x;
  if (b < 1563) {                       // fp32 -> bf16, 8 elems/thread
    int i = b * 256 + t;
    if (i < NN * 64 / 8) {
      const float4* p = (const float4*)features + (size_t)i * 2;
      float4 a = p[0], c = p[1];
      bf16_8 v = {(__bf16)a.x, (__bf16)a.y, (__bf16)a.z, (__bf16)a.w,
                  (__bf16)c.x, (__bf16)c.y, (__bf16)c.z, (__bf16)c.w};
      *(bf16_8*)(fbf + (size_t)i * 8) = v;
    }
  } else if (b < 1563 + 128) {          // Bt0 (512x64): W0^T | Wres0^T
    int idx = (b - 1563) * 256 + t;
    int j = idx >> 6, k = idx & 63;
    float v = (j < 256) ? W0[k * 256 + j] : Wres0[k * 256 + (j - 256)];
    Bt0[idx] = (__bf16)v;
  } else if (b < 1563 + 128 + 256) {    // Bt1 (256x256) = W1^T
    int idx = (b - 1563 - 128) * 256 + t;
    int j = idx >> 8, k = idx & 255;
    Bt1[idx] = (__bf16)W1[k * 256 + j];
  } else if (b == 1947) {               // Ve0
    int f = t >> 2, h = t & 3;
    float s = 0.f;
    for (int d = 0; d < 64; ++d) s += We0[f * 256 + h * 64 + d] * ae0[h * 64 + d];
    Ve0[f * 4 + h] = s;
  } else if (b == 1948) {               // Ve1
    int f = t >> 2, h = t & 3;
    float s = 0.f;
    for (int d = 0; d < 64; ++d) s += We1[f * 256 + h * 64 + d] * ae1[h * 64 + d];
    Ve1[f * 4 + h] = s;
  } else {                              // degree count
    int e = (b - 1949) * 256 + t;
    if (e < EE) atomicAdd(&cnt[dst[e]], 1);
  }
}

// ---------------------------------------------------------------- CSR scan (3-phase)
__global__ __launch_bounds__(256) void scan1_kernel(const int* __restrict__ cnt,
                                                    int* __restrict__ scanbuf,
                                                    int* __restrict__ blocksum) {
  __shared__ int s[256];
  int t = threadIdx.x;
  int idx = blockIdx.x * 256 + t;
  int c = (idx < NN) ? cnt[idx] : 0;
  s[t] = c;
  __syncthreads();
  for (int d = 1; d < 256; d <<= 1) {
    int v = (t >= d) ? s[t - d] : 0;
    __syncthreads();
    s[t] += v;
    __syncthreads();
  }
  if (idx < NN) scanbuf[idx] = s[t];
  if (t == 255) blocksum[blockIdx.x] = s[255];
}

__global__ __launch_bounds__(256) void scan2_kernel(const int* __restrict__ blocksum,
                                                    int* __restrict__ blockoff, int nb) {
  __shared__ int s[256];
  int t = threadIdx.x;
  int c = (t < nb) ? blocksum[t] : 0;
  s[t] = c;
  __syncthreads();
  for (int d = 1; d < 256; d <<= 1) {
    int v = (t >= d) ? s[t - d] : 0;
    __syncthreads();
    s[t] += v;
    __syncthreads();
  }
  if (t < nb) blockoff[t] = s[t] - c;  // exclusive
}

__global__ __launch_bounds__(256) void scan3_kernel(const int* __restrict__ scanbuf,
                                                    const int* __restrict__ cnt,
                                                    const int* __restrict__ blockoff,
                                                    int* __restrict__ off,
                                                    int* __restrict__ cur) {
  int idx = blockIdx.x * 256 + threadIdx.x;
  if (idx < NN) {
    int o = blockoff[blockIdx.x] + scanbuf[idx] - cnt[idx];
    off[idx] = o;
    cur[idx] = o;
  }
  if (idx == 0) off[NN] = EE;
}

// records src_csr[p]; pose[e] = CSR slot of edge e (for wk's scattered write)
__global__ __launch_bounds__(256) void fill_kernel(const int* __restrict__ src,
                                                   const int* __restrict__ dst,
                                                   int* __restrict__ cur,
                                                   int* __restrict__ srcc,
                                                   int* __restrict__ pose) {
  int e = blockIdx.x * 256 + threadIdx.x;
  if (e < EE) {
    int p = atomicAdd(&cur[dst[e]], 1);
    srcc[p] = src[e];
    pose[e] = p;
  }
}

// ---------------------------------------------------------------- edge ee pass
// eeo0[e*4+h] = ef[e].Ve0 (heads), eeo1[e*4+h] = ef[e].Ve1 (split planes so the
// per-layer wk pass reads fully coalesced).
__global__ __launch_bounds__(256) void eek_kernel(const float* __restrict__ ef,
                                                  const float* __restrict__ Ve0,
                                                  const float* __restrict__ Ve1,
                                                  float* __restrict__ eeo0,
                                                  float* __restrict__ eeo1) {
  __shared__ float V0[256], V1[256];
  V0[threadIdx.x] = Ve0[threadIdx.x];
  V1[threadIdx.x] = Ve1[threadIdx.x];
  __syncthreads();
  int r = threadIdx.x >> 2, sub = threadIdx.x & 3;
  int e = blockIdx.x * 64 + r;
  if (e >= EE) return;
  float a0 = 0, a1 = 0, a2 = 0, a3 = 0;
  float c0 = 0, c1 = 0, c2 = 0, c3 = 0;
  const float* row = ef + (size_t)e * 64 + sub * 16;
#pragma unroll
  for (int i = 0; i < 16; i += 4) {
    float4 v = *(const float4*)(row + i);
    float xs[4] = {v.x, v.y, v.z, v.w};
#pragma unroll
    for (int j = 0; j < 4; ++j) {
      float x = xs[j];
      int idx = (sub * 16 + i + j) * 4;
      a0 += x * V0[idx + 0]; a1 += x * V0[idx + 1];
      a2 += x * V0[idx + 2]; a3 += x * V0[idx + 3];
      c0 += x * V1[idx + 0]; c1 += x * V1[idx + 1];
      c2 += x * V1[idx + 2]; c3 += x * V1[idx + 3];
    }
  }
#pragma unroll
  for (int o = 1; o < 4; o <<= 1) {
    a0 += __shfl_xor(a0, o); a1 += __shfl_xor(a1, o);
    a2 += __shfl_xor(a2, o); a3 += __shfl_xor(a3, o);
    c0 += __shfl_xor(c0, o); c1 += __shfl_xor(c1, o);
    c2 += __shfl_xor(c2, o); c3 += __shfl_xor(c3, o);
  }
  if (sub == 0) {
    float4 u; u.x = a0; u.y = a1; u.z = a2; u.w = a3;
    float4 w; w.x = c0; w.y = c1; w.z = c2; w.w = c3;
    *(float4*)(eeo0 + (size_t)e * 4) = u;
    *(float4*)(eeo1 + (size_t)e * 4) = w;
  }
}

// ---------------------------------------------------------------- MFMA GEMM
// C[M x NC] = A @ B, Bt: NC x K row-major. cols<256 -> ft (bf16) + fused el/er;
// cols>=256 -> base = val + bias[col-256] (layer 0 residual).
#define LDK 40
__global__ __launch_bounds__(256) void gemm_kernel(const __bf16* __restrict__ A,
                                                   const __bf16* __restrict__ Bt,
                                                   __bf16* __restrict__ ft,
                                                   __bf16* __restrict__ base,
                                                   const float* __restrict__ bias,
                                                   const float* __restrict__ al,
                                                   const float* __restrict__ ar,
                                                   float* __restrict__ el,
                                                   float* __restrict__ er,
                                                   int M, int K) {
  __shared__ __align__(16) __bf16 Al[64 * LDK];
  __shared__ __align__(16) __bf16 Bl[64 * LDK];
  int tid = threadIdx.x;
  int wav = tid >> 6, lane = tid & 63;
  int quad = lane >> 4, l16 = lane & 15;
  int bm = blockIdx.x * 64;
  int bn = blockIdx.y * 64;
  int sr = tid >> 2;
  int sk = (tid & 3) << 3;

  f32x4 acc[4] = {{0, 0, 0, 0}, {0, 0, 0, 0}, {0, 0, 0, 0}, {0, 0, 0, 0}};

  for (int k0 = 0; k0 < K; k0 += 32) {
    uint4 av = {0, 0, 0, 0};
    int arow = bm + sr;
    if (arow < M) av = *(const uint4*)(A + (size_t)arow * K + k0 + sk);
    uint4 bv = *(const uint4*)(Bt + (size_t)(bn + sr) * K + k0 + sk);
    __syncthreads();
    *(uint4*)&Al[sr * LDK + sk] = av;
    *(uint4*)&Bl[sr * LDK + sk] = bv;
    __syncthreads();
    bf16_8 af = *(const bf16_8*)&Al[(wav * 16 + l16) * LDK + quad * 8];
#pragma unroll
    for (int nt = 0; nt < 4; ++nt) {
      bf16_8 bf = *(const bf16_8*)&Bl[(nt * 16 + l16) * LDK + quad * 8];
      acc[nt] = __builtin_amdgcn_mfma_f32_16x16x32_bf16(af, bf, acc[nt], 0, 0, 0);
    }
  }

  int row0 = bm + wav * 16 + quad * 4;

  // fused el/er for head hb = bn/64 (cols < 256 only)
  if (bn < 256) {
    int hb = bn >> 6;
#pragma unroll
    for (int r = 0; r < 4; ++r) {
      float pl = 0.f, pr = 0.f;
#pragma unroll
      for (int nt = 0; nt < 4; ++nt) {
        float v = acc[nt][r];
        int d = nt * 16 + l16;
        pl += v * al[hb * 64 + d];
        pr += v * ar[hb * 64 + d];
      }
#pragma unroll
      for (int o2 = 8; o2 > 0; o2 >>= 1) {
        pl += __shfl_xor(pl, o2);
        pr += __shfl_xor(pr, o2);
      }
      int row = row0 + r;
      if (l16 == 0 && row < M) {
        el[row * 4 + hb] = pl;
        er[row * 4 + hb] = pr;
      }
    }
  }

#pragma unroll
  for (int nt = 0; nt < 4; ++nt) {
    int col = bn + nt * 16 + l16;
#pragma unroll
    for (int r = 0; r < 4; ++r) {
      int row = row0 + r;
      if (row < M) {
        float v = acc[nt][r];
        if (col < 256)
          ft[(size_t)row * 256 + col] = (__bf16)v;
        else
          base[(size_t)row * 256 + (col - 256)] = (__bf16)(v + bias[col - 256]);
      }
    }
  }
}

// ---------------------------------------------------------------- edge weight pass
// Edge-parallel: w[h] = exp(leaky(el[src]+er[dst]+ee[h])), written in CSR order
// via pose[e]. All reads coalesced; el/er gathers hit an 800KB L2-resident table.
__global__ __launch_bounds__(256) void wk_kernel(const int* __restrict__ src,
                                                 const int* __restrict__ dst,
                                                 const int* __restrict__ pose,
                                                 const float* __restrict__ ee,
                                                 const float* __restrict__ el,
                                                 const float* __restrict__ er,
                                                 float* __restrict__ wcsr) {
  int e = blockIdx.x * 256 + threadIdx.x;
  if (e >= EE) return;
  int s = src[e], d = dst[e], p = pose[e];
  float4 z4 = *(const float4*)(ee + (size_t)e * 4);
  float4 e_l = *(const float4*)(el + (size_t)s * 4);
  float4 e_r = *(const float4*)(er + (size_t)d * 4);
  float4 w;
  float z;
  z = e_l.x + e_r.x + z4.x; w.x = __expf(z > 0.f ? z : 0.2f * z);
  z = e_l.y + e_r.y + z4.y; w.y = __expf(z > 0.f ? z : 0.2f * z);
  z = e_l.z + e_r.z + z4.z; w.z = __expf(z > 0.f ? z : 0.2f * z);
  z = e_l.w + e_r.w + z4.w; w.w = __expf(z > 0.f ? z : 0.2f * z);
  *(float4*)(wcsr + (size_t)p * 4) = w;
}

// ---------------------------------------------------------------- agg
// One block per dst node; wave = head. Weights precomputed in CSR order (wcsr).
// Each wave loads a 64-edge chunk of srcc/wcsr into one reg/lane, then iterates
// via readlane (uniform -> SGPR): per edge only {2 readlane, 1 ft gather with
// SGPR base, cvt, fmac, den add}. LAYER 0: +prev, ELU -> outb bf16 (aliases
// prev; same-slot RMW). LAYER 1: +prev+bias, mean heads -> outf fp32.
template <int LAYER>
__global__ __launch_bounds__(256) void agg_kernel(const int* __restrict__ off,
                                                  const int* __restrict__ srcc,
                                                  const float* __restrict__ wcsr,
                                                  const __bf16* __restrict__ ft,
                                                  const __bf16* prev,
                                                  const float* __restrict__ bias,
                                                  __bf16* outb,
                                                  float* __restrict__ outf) {
  __shared__ float red[256];
  int n = blockIdx.x;
  int t = threadIdx.x, h = t >> 6, lane = t & 63;
  int beg = off[n], end = off[n + 1];
  float pv = (float)prev[(size_t)n * 256 + t];
  float bv = (LAYER == 1) ? bias[t] : 0.f;
  int offd = h * 64 + lane;

  float acc = 0.f, den = 0.f;
  for (int c = beg; c < end; c += 64) {
    int rem = end - c;
    if (rem > 64) rem = 64;
    int sv = 0;
    float wv = 0.f;
    if (lane < rem) {
      sv = srcc[c + lane];
      wv = wcsr[(size_t)(c + lane) * 4 + h];
    }
    int k = 0;
    for (; k + 4 <= rem; k += 4) {
      int s0 = __builtin_amdgcn_readlane(sv, k);
      int s1 = __builtin_amdgcn_readlane(sv, k + 1);
      int s2 = __builtin_amdgcn_readlane(sv, k + 2);
      int s3 = __builtin_amdgcn_readlane(sv, k + 3);
      float w0 = __uint_as_float(__builtin_amdgcn_readlane(__float_as_uint(wv), k));
      float w1 = __uint_as_float(__builtin_amdgcn_readlane(__float_as_uint(wv), k + 1));
      float w2 = __uint_as_float(__builtin_amdgcn_readlane(__float_as_uint(wv), k + 2));
      float w3 = __uint_as_float(__builtin_amdgcn_readlane(__float_as_uint(wv), k + 3));
      float v0 = (float)ft[(size_t)s0 * 256 + offd];
      float v1 = (float)ft[(size_t)s1 * 256 + offd];
      float v2 = (float)ft[(size_t)s2 * 256 + offd];
      float v3 = (float)ft[(size_t)s3 * 256 + offd];
      acc += w0 * v0; acc += w1 * v1; acc += w2 * v2; acc += w3 * v3;
      den += w0 + w1 + w2 + w3;
    }
    for (; k < rem; ++k) {
      int s = __builtin_amdgcn_readlane(sv, k);
      float w = __uint_as_float(__builtin_amdgcn_readlane(__float_as_uint(wv), k));
      acc += w * (float)ft[(size_t)s * 256 + offd];
      den += w;
    }
  }
  float res = (end > beg) ? acc / den : 0.f;

  if (LAYER == 0) {
    float v = res + pv;
    v = v > 0.f ? v : (__expf(v) - 1.0f);  // ELU
    outb[(size_t)n * 256 + t] = (__bf16)v;
  } else {
    red[t] = res + pv + bv;
    __syncthreads();
    if (t < 64)
      outf[(size_t)n * 64 + t] =
          0.25f * (red[t] + red[t + 64] + red[t + 128] + red[t + 192]);
  }
}

// ---------------------------------------------------------------- launch
extern "C" void kernel_launch(void* const* d_in, const int* in_sizes, int n_in,
                              void* d_out, int out_size, void* d_ws, size_t ws_size,
                              hipStream_t stream) {
  const float* features  = (const float*)d_in[0];
  const float* edge_feat = (const float*)d_in[1];
  const int*   src       = (const int*)d_in[2];
  const int*   dst       = (const int*)d_in[3];
  const float* W0    = (const float*)d_in[4];
  const float* We0   = (const float*)d_in[5];
  const float* al0   = (const float*)d_in[6];
  const float* ar0   = (const float*)d_in[7];
  const float* ae0   = (const float*)d_in[8];
  const float* b0    = (const float*)d_in[9];
  const float* Wres0 = (const float*)d_in[10];
  const float* W1    = (const float*)d_in[11];
  const float* We1   = (const float*)d_in[12];
  const float* al1   = (const float*)d_in[13];
  const float* ar1   = (const float*)d_in[14];
  const float* ae1   = (const float*)d_in[15];
  const float* b1    = (const float*)d_in[16];
  float* out = (float*)d_out;

  char* ws = (char*)d_ws;
  size_t o = 0;
  auto alloc = [&](size_t bytes) {
    void* p = ws + o;
    o = (o + bytes + 255) & ~(size_t)255;
    return p;
  };
  int*    cnt      = (int*)alloc((size_t)NN * 4);
  int*    scanbuf  = (int*)alloc((size_t)NN * 4);
  int*    blocksum = (int*)alloc(256 * 4);
  int*    blockoff = (int*)alloc(256 * 4);
  int*    off      = (int*)alloc((size_t)(NN + 1) * 4);
  int*    cur      = (int*)alloc((size_t)NN * 4);
  int*    srcc     = (int*)alloc((size_t)EE * 4);
  int*    pose     = (int*)alloc((size_t)EE * 4);
  float*  eeo0     = (float*)alloc((size_t)EE * 4 * 4);
  float*  eeo1     = (float*)alloc((size_t)EE * 4 * 4);
  float*  wcsr     = (float*)alloc((size_t)EE * 4 * 4);
  float*  el       = (float*)alloc((size_t)NN * 4 * 4);
  float*  er       = (float*)alloc((size_t)NN * 4 * 4);
  float*  Ve0      = (float*)alloc(256 * 4);
  float*  Ve1      = (float*)alloc(256 * 4);
  __bf16* Bt0      = (__bf16*)alloc((size_t)512 * 64 * 2);
  __bf16* Bt1      = (__bf16*)alloc((size_t)256 * 256 * 2);
  __bf16* fbf      = (__bf16*)alloc((size_t)NN * 64 * 2);
  __bf16* ft       = (__bf16*)alloc((size_t)NN * 256 * 2);
  __bf16* base     = (__bf16*)alloc((size_t)NN * 256 * 2);  // h1 aliases base
  __bf16* h1       = base;

  const int EB = (EE + 255) / 256;   // 1563
  const int MG = (NN + 63) / 64;     // 782

  hipMemsetAsync(cnt, 0, (size_t)NN * 4, stream);
  prep_kernel<<<1949 + EB, 256, 0, stream>>>(features, fbf, W0, Wres0, Bt0, W1, Bt1,
                                             We0, ae0, Ve0, We1, ae1, Ve1, dst, cnt);
  scan1_kernel<<<NB, 256, 0, stream>>>(cnt, scanbuf, blocksum);
  scan2_kernel<<<1, 256, 0, stream>>>(blocksum, blockoff, NB);
  scan3_kernel<<<NB, 256, 0, stream>>>(scanbuf, cnt, blockoff, off, cur);
  fill_kernel<<<EB, 256, 0, stream>>>(src, dst, cur, srcc, pose);
  eek_kernel<<<(EE + 63) / 64, 256, 0, stream>>>(edge_feat, Ve0, Ve1, eeo0, eeo1);

  // ---- layer 0
  gemm_kernel<<<dim3(MG, 8), 256, 0, stream>>>(fbf, Bt0, ft, base, b0, al0, ar0, el, er, NN, 64);
  wk_kernel<<<EB, 256, 0, stream>>>(src, dst, pose, eeo0, el, er, wcsr);
  agg_kernel<0><<<NN, 256, 0, stream>>>(off, srcc, wcsr, ft, base, nullptr, h1, nullptr);

  // ---- layer 1
  gemm_kernel<<<dim3(MG, 4), 256, 0, stream>>>(h1, Bt1, ft, nullptr, nullptr, al1, ar1, el, er, NN, 256);
  wk_kernel<<<EB, 256, 0, stream>>>(src, dst, pose, eeo1, el, er, wcsr);
  agg_kernel<1><<<NN, 256, 0, stream>>>(off, srcc, wcsr, ft, h1, b1, nullptr, out);
}

// Round 2
// 410.209 us; speedup vs baseline: 1.0844x; 1.0642x over previous
//
#include <hip/hip_runtime.h>
#include <hip/hip_bf16.h>

#define NN 50000
#define EE 400000
#define NB 196  // ceil(NN/256)

typedef __bf16 bf16_8 __attribute__((ext_vector_type(8)));
typedef __bf16 bf16_2 __attribute__((ext_vector_type(2)));
typedef float f32x4 __attribute__((ext_vector_type(4)));
typedef float f32x2 __attribute__((ext_vector_type(2)));

// unpack 2 packed bf16 (one dword) -> 2 f32 (exact, 2 bitops)
__device__ inline f32x2 bf2(unsigned u) {
  f32x2 r;
  r.x = __uint_as_float(u << 16);
  r.y = __uint_as_float(u & 0xffff0000u);
  return r;
}

// ---------------------------------------------------------------- prep (fused)
// [0,1563): f2b; [1563,1691): tr0; [1691,1947): tr1; 1947: ve0; 1948: ve1;
// [1949, 1949+1563): degree count (cnt zeroed by memset before launch)
__global__ __launch_bounds__(256) void prep_kernel(
    const float* __restrict__ features, __bf16* __restrict__ fbf,
    const float* __restrict__ W0, const float* __restrict__ Wres0, __bf16* __restrict__ Bt0,
    const float* __restrict__ W1, __bf16* __restrict__ Bt1,
    const float* __restrict__ We0, const float* __restrict__ ae0, float* __restrict__ Ve0,
    const float* __restrict__ We1, const float* __restrict__ ae1, float* __restrict__ Ve1,
    const int* __restrict__ dst, int* __restrict__ cnt) {
  int b = blockIdx.x;
  int t = threadIdx.x;
  if (b < 1563) {                       // fp32 -> bf16, 8 elems/thread
    int i = b * 256 + t;
    if (i < NN * 64 / 8) {
      const float4* p = (const float4*)features + (size_t)i * 2;
      float4 a = p[0], c = p[1];
      bf16_8 v = {(__bf16)a.x, (__bf16)a.y, (__bf16)a.z, (__bf16)a.w,
                  (__bf16)c.x, (__bf16)c.y, (__bf16)c.z, (__bf16)c.w};
      *(bf16_8*)(fbf + (size_t)i * 8) = v;
    }
  } else if (b < 1563 + 128) {          // Bt0 (512x64): W0^T | Wres0^T
    int idx = (b - 1563) * 256 + t;
    int j = idx >> 6, k = idx & 63;
    float v = (j < 256) ? W0[k * 256 + j] : Wres0[k * 256 + (j - 256)];
    Bt0[idx] = (__bf16)v;
  } else if (b < 1563 + 128 + 256) {    // Bt1 (256x256) = W1^T
    int idx = (b - 1563 - 128) * 256 + t;
    int j = idx >> 8, k = idx & 255;
    Bt1[idx] = (__bf16)W1[k * 256 + j];
  } else if (b == 1947) {               // Ve0
    int f = t >> 2, h = t & 3;
    float s = 0.f;
    for (int d = 0; d < 64; ++d) s += We0[f * 256 + h * 64 + d] * ae0[h * 64 + d];
    Ve0[f * 4 + h] = s;
  } else if (b == 1948) {               // Ve1
    int f = t >> 2, h = t & 3;
    float s = 0.f;
    for (int d = 0; d < 64; ++d) s += We1[f * 256 + h * 64 + d] * ae1[h * 64 + d];
    Ve1[f * 4 + h] = s;
  } else {                              // degree count
    int e = (b - 1949) * 256 + t;
    if (e < EE) atomicAdd(&cnt[dst[e]], 1);
  }
}

// ---------------------------------------------------------------- CSR scan (3-phase)
__global__ __launch_bounds__(256) void scan1_kernel(const int* __restrict__ cnt,
                                                    int* __restrict__ scanbuf,
                                                    int* __restrict__ blocksum) {
  __shared__ int s[256];
  int t = threadIdx.x;
  int idx = blockIdx.x * 256 + t;
  int c = (idx < NN) ? cnt[idx] : 0;
  s[t] = c;
  __syncthreads();
  for (int d = 1; d < 256; d <<= 1) {
    int v = (t >= d) ? s[t - d] : 0;
    __syncthreads();
    s[t] += v;
    __syncthreads();
  }
  if (idx < NN) scanbuf[idx] = s[t];
  if (t == 255) blocksum[blockIdx.x] = s[255];
}

__global__ __launch_bounds__(256) void scan2_kernel(const int* __restrict__ blocksum,
                                                    int* __restrict__ blockoff, int nb) {
  __shared__ int s[256];
  int t = threadIdx.x;
  int c = (t < nb) ? blocksum[t] : 0;
  s[t] = c;
  __syncthreads();
  for (int d = 1; d < 256; d <<= 1) {
    int v = (t >= d) ? s[t - d] : 0;
    __syncthreads();
    s[t] += v;
    __syncthreads();
  }
  if (t < nb) blockoff[t] = s[t] - c;  // exclusive
}

__global__ __launch_bounds__(256) void scan3_kernel(const int* __restrict__ scanbuf,
                                                    const int* __restrict__ cnt,
                                                    const int* __restrict__ blockoff,
                                                    int* __restrict__ off,
                                                    int* __restrict__ cur) {
  int idx = blockIdx.x * 256 + threadIdx.x;
  if (idx < NN) {
    int o = blockoff[blockIdx.x] + scanbuf[idx] - cnt[idx];
    off[idx] = o;
    cur[idx] = o;
  }
  if (idx == 0) off[NN] = EE;
}

// records src_csr[p]; pose[e] = CSR slot of edge e (for wk's scattered write)
__global__ __launch_bounds__(256) void fill_kernel(const int* __restrict__ src,
                                                   const int* __restrict__ dst,
                                                   int* __restrict__ cur,
                                                   int* __restrict__ srcc,
                                                   int* __restrict__ pose) {
  int e = blockIdx.x * 256 + threadIdx.x;
  if (e < EE) {
    int p = atomicAdd(&cur[dst[e]], 1);
    srcc[p] = src[e];
    pose[e] = p;
  }
}

// ---------------------------------------------------------------- edge ee pass
// eeo0[e*4+h] = ef[e].Ve0 (heads), eeo1[e*4+h] = ef[e].Ve1 (split planes so the
// per-layer wk pass reads fully coalesced).
__global__ __launch_bounds__(256) void eek_kernel(const float* __restrict__ ef,
                                                  const float* __restrict__ Ve0,
                                                  const float* __restrict__ Ve1,
                                                  float* __restrict__ eeo0,
                                                  float* __restrict__ eeo1) {
  __shared__ float V0[256], V1[256];
  V0[threadIdx.x] = Ve0[threadIdx.x];
  V1[threadIdx.x] = Ve1[threadIdx.x];
  __syncthreads();
  int r = threadIdx.x >> 2, sub = threadIdx.x & 3;
  int e = blockIdx.x * 64 + r;
  if (e >= EE) return;
  float a0 = 0, a1 = 0, a2 = 0, a3 = 0;
  float c0 = 0, c1 = 0, c2 = 0, c3 = 0;
  const float* row = ef + (size_t)e * 64 + sub * 16;
#pragma unroll
  for (int i = 0; i < 16; i += 4) {
    float4 v = *(const float4*)(row + i);
    float xs[4] = {v.x, v.y, v.z, v.w};
#pragma unroll
    for (int j = 0; j < 4; ++j) {
      float x = xs[j];
      int idx = (sub * 16 + i + j) * 4;
      a0 += x * V0[idx + 0]; a1 += x * V0[idx + 1];
      a2 += x * V0[idx + 2]; a3 += x * V0[idx + 3];
      c0 += x * V1[idx + 0]; c1 += x * V1[idx + 1];
      c2 += x * V1[idx + 2]; c3 += x * V1[idx + 3];
    }
  }
#pragma unroll
  for (int o = 1; o < 4; o <<= 1) {
    a0 += __shfl_xor(a0, o); a1 += __shfl_xor(a1, o);
    a2 += __shfl_xor(a2, o); a3 += __shfl_xor(a3, o);
    c0 += __shfl_xor(c0, o); c1 += __shfl_xor(c1, o);
    c2 += __shfl_xor(c2, o); c3 += __shfl_xor(c3, o);
  }
  if (sub == 0) {
    float4 u; u.x = a0; u.y = a1; u.z = a2; u.w = a3;
    float4 w; w.x = c0; w.y = c1; w.z = c2; w.w = c3;
    *(float4*)(eeo0 + (size_t)e * 4) = u;
    *(float4*)(eeo1 + (size_t)e * 4) = w;
  }
}

// ---------------------------------------------------------------- MFMA GEMM
// C[M x NC] = A @ B, Bt: NC x K row-major. cols<256 -> ft (bf16) + fused el/er;
// cols>=256 -> base = val + bias[col-256] (layer 0 residual).
#define LDK 40
__global__ __launch_bounds__(256) void gemm_kernel(const __bf16* __restrict__ A,
                                                   const __bf16* __restrict__ Bt,
                                                   __bf16* __restrict__ ft,
                                                   __bf16* __restrict__ base,
                                                   const float* __restrict__ bias,
                                                   const float* __restrict__ al,
                                                   const float* __restrict__ ar,
                                                   float* __restrict__ el,
                                                   float* __restrict__ er,
                                                   int M, int K) {
  __shared__ __align__(16) __bf16 Al[64 * LDK];
  __shared__ __align__(16) __bf16 Bl[64 * LDK];
  int tid = threadIdx.x;
  int wav = tid >> 6, lane = tid & 63;
  int quad = lane >> 4, l16 = lane & 15;
  int bm = blockIdx.x * 64;
  int bn = blockIdx.y * 64;
  int sr = tid >> 2;
  int sk = (tid & 3) << 3;

  f32x4 acc[4] = {{0, 0, 0, 0}, {0, 0, 0, 0}, {0, 0, 0, 0}, {0, 0, 0, 0}};

  for (int k0 = 0; k0 < K; k0 += 32) {
    uint4 av = {0, 0, 0, 0};
    int arow = bm + sr;
    if (arow < M) av = *(const uint4*)(A + (size_t)arow * K + k0 + sk);
    uint4 bv = *(const uint4*)(Bt + (size_t)(bn + sr) * K + k0 + sk);
    __syncthreads();
    *(uint4*)&Al[sr * LDK + sk] = av;
    *(uint4*)&Bl[sr * LDK + sk] = bv;
    __syncthreads();
    bf16_8 af = *(const bf16_8*)&Al[(wav * 16 + l16) * LDK + quad * 8];
#pragma unroll
    for (int nt = 0; nt < 4; ++nt) {
      bf16_8 bf = *(const bf16_8*)&Bl[(nt * 16 + l16) * LDK + quad * 8];
      acc[nt] = __builtin_amdgcn_mfma_f32_16x16x32_bf16(af, bf, acc[nt], 0, 0, 0);
    }
  }

  int row0 = bm + wav * 16 + quad * 4;

  // fused el/er for head hb = bn/64 (cols < 256 only)
  if (bn < 256) {
    int hb = bn >> 6;
#pragma unroll
    for (int r = 0; r < 4; ++r) {
      float pl = 0.f, pr = 0.f;
#pragma unroll
      for (int nt = 0; nt < 4; ++nt) {
        float v = acc[nt][r];
        int d = nt * 16 + l16;
        pl += v * al[hb * 64 + d];
        pr += v * ar[hb * 64 + d];
      }
#pragma unroll
      for (int o2 = 8; o2 > 0; o2 >>= 1) {
        pl += __shfl_xor(pl, o2);
        pr += __shfl_xor(pr, o2);
      }
      int row = row0 + r;
      if (l16 == 0 && row < M) {
        el[row * 4 + hb] = pl;
        er[row * 4 + hb] = pr;
      }
    }
  }

#pragma unroll
  for (int nt = 0; nt < 4; ++nt) {
    int col = bn + nt * 16 + l16;
#pragma unroll
    for (int r = 0; r < 4; ++r) {
      int row = row0 + r;
      if (row < M) {
        float v = acc[nt][r];
        if (col < 256)
          ft[(size_t)row * 256 + col] = (__bf16)v;
        else
          base[(size_t)row * 256 + (col - 256)] = (__bf16)(v + bias[col - 256]);
      }
    }
  }
}

// ---------------------------------------------------------------- edge weight pass
// Edge-parallel: w[h] = exp(leaky(el[src]+er[dst]+ee[h])), written in CSR order
// via pose[e]. All reads coalesced; el/er gathers hit an 800KB L2-resident table.
__global__ __launch_bounds__(256) void wk_kernel(const int* __restrict__ src,
                                                 const int* __restrict__ dst,
                                                 const int* __restrict__ pose,
                                                 const float* __restrict__ ee,
                                                 const float* __restrict__ el,
                                                 const float* __restrict__ er,
                                                 float* __restrict__ wcsr) {
  int e = blockIdx.x * 256 + threadIdx.x;
  if (e >= EE) return;
  int s = src[e], d = dst[e], p = pose[e];
  float4 z4 = *(const float4*)(ee + (size_t)e * 4);
  float4 e_l = *(const float4*)(el + (size_t)s * 4);
  float4 e_r = *(const float4*)(er + (size_t)d * 4);
  float4 w;
  float z;
  z = e_l.x + e_r.x + z4.x; w.x = __expf(z > 0.f ? z : 0.2f * z);
  z = e_l.y + e_r.y + z4.y; w.y = __expf(z > 0.f ? z : 0.2f * z);
  z = e_l.z + e_r.z + z4.z; w.z = __expf(z > 0.f ? z : 0.2f * z);
  z = e_l.w + e_r.w + z4.w; w.w = __expf(z > 0.f ? z : 0.2f * z);
  *(float4*)(wcsr + (size_t)p * 4) = w;
}

// ---------------------------------------------------------------- agg
// 2 nodes per block (node = wav>>1); 2 waves per node; each wave covers 2 heads
// (head = (wav&1)*2 + lane/32), each lane holds a bf16x2 dim-pair -> packed
// f32x2 FMA (v_pk_fma_f32). Per-chunk (32 edges): srcc+wcsr chunk load; weights
// staged DUPLICATED into LDS as {w,w} so the inner loop gets the pk-fma B
// operand with a single ds_read_b64 (DS pipe, zero VALU). Denominator is
// accumulated from each lane's own chunk-load wv and reduced once via shfl_xor
// at the end (zero per-edge den cost). Inner loop per edge per wave:
// 1 readlane + 1 ds_read_b64 + 1 global_load_dword (SGPR base) + 2 unpack
// bitops + 1 pk_fma. LAYER 0: +prev, ELU -> outb bf16 (aliases prev).
// LAYER 1: +prev+bias, mean heads -> outf fp32.
template <int LAYER>
__global__ __launch_bounds__(256) void agg_kernel(const int* __restrict__ off,
                                                  const int* __restrict__ srcc,
                                                  const float* __restrict__ wcsr,
                                                  const __bf16* __restrict__ ft,
                                                  const __bf16* prev,
                                                  const float* __restrict__ bias,
                                                  __bf16* outb,
                                                  float* __restrict__ outf) {
  __shared__ f32x2 wl2[2][4][32];
  __shared__ f32x2 red2[2][4][32];
  int t = threadIdx.x;
  int wav = t >> 6, lane = t & 63;
  int nh = wav >> 1;            // node half within block
  int hf = lane >> 5;           // half-wave
  int head = ((wav & 1) << 1) + hf;
  int k32 = lane & 31;
  int n = blockIdx.x * 2 + nh;
  int beg = off[n], end = off[n + 1];
  int offb = head * 128 + k32 * 4;  // byte offset within 512B ft row

  const char* ftb = (const char*)ft;
  f32x2 acc0 = {0.f, 0.f}, acc1 = {0.f, 0.f};
  float denp = 0.f;

  for (int c = beg; c < end; c += 32) {
    int rem = end - c;
    if (rem > 32) rem = 32;
    int sv = 0;
    float wv = 0.f;
    if (k32 < rem) {
      sv = srcc[c + k32];
      wv = wcsr[(size_t)(c + k32) * 4 + head];
    }
    denp += wv;
    f32x2 wd = {wv, wv};
    wl2[nh][head][k32] = wd;
    int kk = 0;
    for (; kk + 4 <= rem; kk += 4) {
      int s0 = __builtin_amdgcn_readlane(sv, kk);
      int s1 = __builtin_amdgcn_readlane(sv, kk + 1);
      int s2 = __builtin_amdgcn_readlane(sv, kk + 2);
      int s3 = __builtin_amdgcn_readlane(sv, kk + 3);
      unsigned u0 = *(const unsigned*)(ftb + (size_t)s0 * 512 + offb);
      unsigned u1 = *(const unsigned*)(ftb + (size_t)s1 * 512 + offb);
      unsigned u2 = *(const unsigned*)(ftb + (size_t)s2 * 512 + offb);
      unsigned u3 = *(const unsigned*)(ftb + (size_t)s3 * 512 + offb);
      f32x2 w0 = wl2[nh][head][kk];
      f32x2 w1 = wl2[nh][head][kk + 1];
      f32x2 w2 = wl2[nh][head][kk + 2];
      f32x2 w3 = wl2[nh][head][kk + 3];
      acc0 = __builtin_elementwise_fma(bf2(u0), w0, acc0);
      acc1 = __builtin_elementwise_fma(bf2(u1), w1, acc1);
      acc0 = __builtin_elementwise_fma(bf2(u2), w2, acc0);
      acc1 = __builtin_elementwise_fma(bf2(u3), w3, acc1);
    }
    for (; kk < rem; ++kk) {
      int s0 = __builtin_amdgcn_readlane(sv, kk);
      unsigned u0 = *(const unsigned*)(ftb + (size_t)s0 * 512 + offb);
      f32x2 w0 = wl2[nh][head][kk];
      acc0 = __builtin_elementwise_fma(bf2(u0), w0, acc0);
    }
  }
#pragma unroll
  for (int m = 16; m; m >>= 1) denp += __shfl_xor(denp, m);

  f32x2 res = {0.f, 0.f};
  if (end > beg) {
    float rd = 1.f / denp;
    res.x = (acc0.x + acc1.x) * rd;
    res.y = (acc0.y + acc1.y) * rd;
  }

  unsigned pu = *(const unsigned*)((const char*)prev + (size_t)n * 512 + offb);
  f32x2 pv = bf2(pu);

  if (LAYER == 0) {
    float vx = res.x + pv.x;
    float vy = res.y + pv.y;
    vx = vx > 0.f ? vx : (__expf(vx) - 1.0f);  // ELU
    vy = vy > 0.f ? vy : (__expf(vy) - 1.0f);
    bf16_2 o = {(__bf16)vx, (__bf16)vy};
    *(bf16_2*)((char*)outb + (size_t)n * 512 + offb) = o;
  } else {
    f32x2 bv = *(const f32x2*)(bias + head * 64 + 2 * k32);
    f32x2 rv = {res.x + pv.x + bv.x, res.y + pv.y + bv.y};
    red2[nh][head][k32] = rv;
    __syncthreads();
    if ((wav & 1) == 0 && hf == 0) {
      f32x2 a = red2[nh][0][k32];
      f32x2 b = red2[nh][1][k32];
      f32x2 c = red2[nh][2][k32];
      f32x2 d = red2[nh][3][k32];
      f32x2 s = {0.25f * (a.x + b.x + c.x + d.x), 0.25f * (a.y + b.y + c.y + d.y)};
      *(f32x2*)(outf + (size_t)n * 64 + 2 * k32) = s;
    }
  }
}

// ---------------------------------------------------------------- launch
extern "C" void kernel_launch(void* const* d_in, const int* in_sizes, int n_in,
                              void* d_out, int out_size, void* d_ws, size_t ws_size,
                              hipStream_t stream) {
  const float* features  = (const float*)d_in[0];
  const float* edge_feat = (const float*)d_in[1];
  const int*   src       = (const int*)d_in[2];
  const int*   dst       = (const int*)d_in[3];
  const float* W0    = (const float*)d_in[4];
  const float* We0   = (const float*)d_in[5];
  const float* al0   = (const float*)d_in[6];
  const float* ar0   = (const float*)d_in[7];
  const float* ae0   = (const float*)d_in[8];
  const float* b0    = (const float*)d_in[9];
  const float* Wres0 = (const float*)d_in[10];
  const float* W1    = (const float*)d_in[11];
  const float* We1   = (const float*)d_in[12];
  const float* al1   = (const float*)d_in[13];
  const float* ar1   = (const float*)d_in[14];
  const float* ae1   = (const float*)d_in[15];
  const float* b1    = (const float*)d_in[16];
  float* out = (float*)d_out;

  char* ws = (char*)d_ws;
  size_t o = 0;
  auto alloc = [&](size_t bytes) {
    void* p = ws + o;
    o = (o + bytes + 255) & ~(size_t)255;
    return p;
  };
  int*    cnt      = (int*)alloc((size_t)NN * 4);
  int*    scanbuf  = (int*)alloc((size_t)NN * 4);
  int*    blocksum = (int*)alloc(256 * 4);
  int*    blockoff = (int*)alloc(256 * 4);
  int*    off      = (int*)alloc((size_t)(NN + 1) * 4);
  int*    cur      = (int*)alloc((size_t)NN * 4);
  int*    srcc     = (int*)alloc((size_t)EE * 4);
  int*    pose     = (int*)alloc((size_t)EE * 4);
  float*  eeo0     = (float*)alloc((size_t)EE * 4 * 4);
  float*  eeo1     = (float*)alloc((size_t)EE * 4 * 4);
  float*  wcsr     = (float*)alloc((size_t)EE * 4 * 4);
  float*  el       = (float*)alloc((size_t)NN * 4 * 4);
  float*  er       = (float*)alloc((size_t)NN * 4 * 4);
  float*  Ve0      = (float*)alloc(256 * 4);
  float*  Ve1      = (float*)alloc(256 * 4);
  __bf16* Bt0      = (__bf16*)alloc((size_t)512 * 64 * 2);
  __bf16* Bt1      = (__bf16*)alloc((size_t)256 * 256 * 2);
  __bf16* fbf      = (__bf16*)alloc((size_t)NN * 64 * 2);
  __bf16* ft       = (__bf16*)alloc((size_t)NN * 256 * 2);
  __bf16* base     = (__bf16*)alloc((size_t)NN * 256 * 2);  // h1 aliases base
  __bf16* h1       = base;

  const int EB = (EE + 255) / 256;   // 1563
  const int MG = (NN + 63) / 64;     // 782

  hipMemsetAsync(cnt, 0, (size_t)NN * 4, stream);
  prep_kernel<<<1949 + EB, 256, 0, stream>>>(features, fbf, W0, Wres0, Bt0, W1, Bt1,
                                             We0, ae0, Ve0, We1, ae1, Ve1, dst, cnt);
  scan1_kernel<<<NB, 256, 0, stream>>>(cnt, scanbuf, blocksum);
  scan2_kernel<<<1, 256, 0, stream>>>(blocksum, blockoff, NB);
  scan3_kernel<<<NB, 256, 0, stream>>>(scanbuf, cnt, blockoff, off, cur);
  fill_kernel<<<EB, 256, 0, stream>>>(src, dst, cur, srcc, pose);
  eek_kernel<<<(EE + 63) / 64, 256, 0, stream>>>(edge_feat, Ve0, Ve1, eeo0, eeo1);

  // ---- layer 0
  gemm_kernel<<<dim3(MG, 8), 256, 0, stream>>>(fbf, Bt0, ft, base, b0, al0, ar0, el, er, NN, 64);
  wk_kernel<<<EB, 256, 0, stream>>>(src, dst, pose, eeo0, el, er, wcsr);
  agg_kernel<0><<<NN / 2, 256, 0, stream>>>(off, srcc, wcsr, ft, base, nullptr, h1, nullptr);

  // ---- layer 1
  gemm_kernel<<<dim3(MG, 4), 256, 0, stream>>>(h1, Bt1, ft, nullptr, nullptr, al1, ar1, el, er, NN, 256);
  wk_kernel<<<EB, 256, 0, stream>>>(src, dst, pose, eeo1, el, er, wcsr);
  agg_kernel<1><<<NN / 2, 256, 0, stream>>>(off, srcc, wcsr, ft, h1, b1, nullptr, out);
}